// Round 1
// baseline (42.376 us; speedup 1.0000x reference)
//
#include <hip/hip_runtime.h>
#include <hip/hip_bf16.h>

// SparseLinear: y = W @ x + B
//   W: (8192, 8192) f32, row-major (out_dims x in_dims)  -- d_in[0]
//   B: (8192,) f32                                        -- d_in[1]
//   x: (8192,) f32                                        -- d_in[2]
//   y: (8192,) f32                                        -- d_out
//
// Memory-bound: W is 256 MiB, read exactly once. One wave per output row,
// 4 rows per 256-thread block, 2048 blocks = 8192 waves (fills the chip).

#define IN_DIMS 8192
#define OUT_DIMS 8192

__global__ __launch_bounds__(256) void sparse_linear_matvec(
    const float* __restrict__ W,
    const float* __restrict__ B,
    const float* __restrict__ x,
    float* __restrict__ y) {
    const int wave = threadIdx.x >> 6;   // 0..3
    const int lane = threadIdx.x & 63;   // 0..63
    const int row  = blockIdx.x * 4 + wave;

    const float4* __restrict__ Wr =
        reinterpret_cast<const float4*>(W + (size_t)row * IN_DIMS);
    const float4* __restrict__ xv = reinterpret_cast<const float4*>(x);

    float acc = 0.0f;
    // 8192 floats / row = 2048 float4; 64 lanes -> 32 float4 per lane.
    #pragma unroll
    for (int j = 0; j < 32; ++j) {
        const int idx = lane + 64 * j;          // coalesced: 1 KiB per wave/instr
        float4 w  = Wr[idx];
        float4 xx = xv[idx];                    // L1/L2-resident after first block
        acc += w.x * xx.x + w.y * xx.y + w.z * xx.z + w.w * xx.w;
    }

    // 64-lane butterfly reduction
    #pragma unroll
    for (int off = 32; off > 0; off >>= 1)
        acc += __shfl_down(acc, off, 64);

    if (lane == 0)
        y[row] = acc + B[row];
}

extern "C" void kernel_launch(void* const* d_in, const int* in_sizes, int n_in,
                              void* d_out, int out_size, void* d_ws, size_t ws_size,
                              hipStream_t stream) {
    const float* W = (const float*)d_in[0];
    const float* B = (const float*)d_in[1];
    const float* x = (const float*)d_in[2];
    float* y = (float*)d_out;

    dim3 grid(OUT_DIMS / 4);   // 2048 blocks, 4 rows each
    dim3 block(256);
    sparse_linear_matvec<<<grid, block, 0, stream>>>(W, B, x, y);
}